// Round 9
// baseline (393.374 us; speedup 1.0000x reference)
//
#include <hip/hip_runtime.h>
#include <stdint.h>

// Problem constants
#define T_SEQ 1024
#define B_SZ  16
#define C_IN  1024
#define C_HID 1024
#define M_ROWS (T_SEQ * B_SZ)   // 16384
#define N_COLS (2 * C_HID)      // 2048  (col 2h = Z_h, col 2h+1 = F_h)
#define K_DIM  (2 * C_IN)       // 2048  (k<1024: X[t-1], k>=1024: X[t])

#define NCHUNK 64
#define CLEN   (T_SEQ / NCHUNK) // 16 = rows-per-GEMM-block / B_SZ -> 1 chunk/block
#define NBH    (B_SZ * C_HID)   // 16384 channels

typedef __attribute__((ext_vector_type(8))) short bf16x8;
typedef __attribute__((ext_vector_type(4))) float f32x4;
typedef unsigned short u16;

#define MFMA __builtin_amdgcn_mfma_f32_16x16x32_bf16

__device__ __forceinline__ u16 f2bf(float f) {
  union { float f; unsigned u; } v; v.f = f;
  unsigned r = v.u + 0x7fffu + ((v.u >> 16) & 1u);  // RNE
  return (u16)(r >> 16);
}
__device__ __forceinline__ float bf2f(unsigned s) {
  union { unsigned u; float f; } v; v.u = s << 16;
  return v.f;
}

// async global->LDS, 16B per lane. LDS dest is wave-uniform base + lane*16.
__device__ __forceinline__ void async_cp16(const u16* g, u16* l) {
  __builtin_amdgcn_global_load_lds(
      (const __attribute__((address_space(1))) unsigned*)(uintptr_t)g,
      (__attribute__((address_space(3))) unsigned*)(uintptr_t)l,
      16, 0, 0);
}

// ---------------------------------------------------------------------------
// Kernel 1 (fused prep): blocks [0,16400) convert X f32->bf16 with one
// leading zero time-step; blocks [16400,24592) repack Wz/Wf -> Wt
// (N=2048,K=2048) bf16 B^T, Z/F interleaved (row 2h = Wz[h], 2h+1 = Wf[h]).
// ---------------------------------------------------------------------------
__global__ __launch_bounds__(256) void k_prep(const float* __restrict__ X,
                                              const float* __restrict__ Wz,
                                              const float* __restrict__ Wf,
                                              u16* __restrict__ Xp,
                                              u16* __restrict__ Wt) {
  int blk = blockIdx.x;
  if (blk < 16400) {
    int i = blk * 256 + threadIdx.x;            // one thread = 4 elems
    const int total4 = (M_ROWS + B_SZ) * C_IN / 4;
    if (i >= total4) return;
    int e = i << 2;
    const int PAD = B_SZ * C_IN;  // 16384
    ushort4 o;
    if (e < PAD) {
      o.x = o.y = o.z = o.w = 0;
    } else {
      float4 v = *reinterpret_cast<const float4*>(X + (e - PAD));
      o.x = f2bf(v.x); o.y = f2bf(v.y); o.z = f2bf(v.z); o.w = f2bf(v.w);
    }
    *reinterpret_cast<ushort4*>(Xp + e) = o;
  } else {
    int i = (blk - 16400) * 256 + threadIdx.x;  // one thread = one (g,h,c)
    if (i >= 2 * 1024 * 1024) return;
    int g  = i >> 20;
    int hc = i & ((1 << 20) - 1);
    int h  = hc >> 10;
    int c  = hc & 1023;
    const float* W = g ? Wf : Wz;
    float2 w = *reinterpret_cast<const float2*>(W + ((size_t)(h << 10) + c) * 2);
    size_t n = ((size_t)h << 1) | (size_t)g;   // interleave Z/F
    Wt[n * K_DIM + c]        = f2bf(w.x);      // k = 0 tap
    Wt[n * K_DIM + 1024 + c] = f2bf(w.y);      // k = 1 tap
  }
}

// ---------------------------------------------------------------------------
// Kernel 2: 256x256-tile bf16 GEMM, software-pipelined ds_reads.
// NEW K-loop (vs round 5/7/8): reads issue ONE PHASE AHEAD of their MFMA with
// COMPILER-counted lgkm waits (no lgkmcnt(0) drains) so the LDS unit services
// reads DURING the previous MFMA cluster. 4 barriers/tile instead of 8.
// WAR safety (region: read-issue / consuming-MFMA / overwriting-stage):
//   A_lo: P4(t-1) / P1 / stage(4t+10)@P4   B0: P4(t-1) / P1 / stage(4t+8)@P2
//   B1:   P1      / P2 / stage(4t+9)@P3    A_hi: P2    / P3 / stage(4t+11)@P1(t+1)
// Each overwrite issues >=1 barrier after its region's consuming MFMA.
// vmcnt(6)@P4 guarantees tile t+1 fully landed (j<=4t+7); t>=30 drains to 0.
// Epilogue (round-8 verified): activation + in-register 16-step chunk scan;
// Cb word = bf16(Hpart) | bf16(Ppre)<<16,  h_t(h0) = Hpart + Ppre*h0.
// ---------------------------------------------------------------------------
__global__ __launch_bounds__(512, 2) void k_gemm8(const u16* __restrict__ Xp,
                                                  const u16* __restrict__ Wt,
                                                  const float* __restrict__ bz,
                                                  const float* __restrict__ bfv,
                                                  u16* __restrict__ Cb) {
  __shared__ u16 lds[2][2][2][8192];  // [buf][A=0/B=1][half][128*64] = 128 KiB
  const int tid  = threadIdx.x;
  const int lane = tid & 63;
  const int wid  = tid >> 6;
  const int wr = wid >> 2;        // m-half of this wave
  const int wc = wid & 3;         // n-quarter
  const int lr = lane & 15;

  // T1: XCD-bijective swizzle (512 blocks, 512%8==0), n-fastest within XCD
  int wg = (blockIdx.x & 7) * 64 + (blockIdx.x >> 3);
  const int m0 = (wg >> 3) << 8;
  const int n0 = (wg & 7) << 8;

  // staging per-thread coords: linear LDS byte p -> logical source byte q
  const int p    = tid << 4;
  const int q    = p ^ (((p >> 7) & 7) << 4);   // involution (bits 4-6 vs 7-9)
  const int grow = q >> 7;                      // logical row 0..63 (issue 0)
  const int gcol = (q & 127) >> 1;              // logical col element
  const int ldsw = (tid >> 6) << 9;             // u16 wave base (wid*1KB)

  // ds_read per-thread coords (u16 units), swizzled column offset
  const int rbase = lr << 6;
  int co[2];
#pragma unroll
  for (int ks = 0; ks < 2; ++ks)
    co[ks] = ((((ks << 6) | ((lane >> 4) << 4)) ^ ((lr & 7) << 4)) >> 1);

  auto stage = [&](int j) {   // j = 4*kt + {0:B0,1:B1,2:A0,3:A1}
    int kt = j >> 2, part = j & 3, buf = kt & 1;
    if (part >= 2) {
      int h = part - 2;
      const u16* g = Xp + (size_t)(m0 + (h << 7) + grow + ((kt >= 16) ? B_SZ : 0)) * C_IN
                        + ((kt & 15) << 6) + gcol;
      u16* l = &lds[buf][0][h][ldsw];
      async_cp16(g, l);
      async_cp16(g + (size_t)64 * C_IN, l + 4096);
    } else {
      const u16* g = Wt + (size_t)(n0 + (part << 7) + grow) * K_DIM + (kt << 6) + gcol;
      u16* l = &lds[buf][1][part][ldsw];
      async_cp16(g, l);
      async_cp16(g + (size_t)64 * K_DIM, l + 4096);
    }
  };

  f32x4 acc[8][4] = {};
  bf16x8 a[4][2], a2[4][2], aN[4][2], b0[2][2], b0N[2][2], b1[2][2];

  // prologue: stage tile0 + tile1 B0,B1,A0 (j0..6); tile0 landed at vmcnt(6);
  // pre-read tile0's a_lo + b0.
  for (int j = 0; j < 7; ++j) stage(j);
  asm volatile("s_waitcnt vmcnt(6)" ::: "memory");
  __builtin_amdgcn_s_barrier();
  {
    const u16* pA = &lds[0][0][wr][0];
    const u16* pB = &lds[0][1][wc >> 1][(wc & 1) << 12];
#pragma unroll
    for (int mi = 0; mi < 4; ++mi)
#pragma unroll
      for (int ks = 0; ks < 2; ++ks)
        a[mi][ks] = *(const bf16x8*)(pA + (mi << 10) + rbase + co[ks]);
#pragma unroll
    for (int ni = 0; ni < 2; ++ni)
#pragma unroll
      for (int ks = 0; ks < 2; ++ks)
        b0[ni][ks] = *(const bf16x8*)(pB + (ni << 10) + rbase + co[ks]);
  }

#pragma unroll 2
  for (int t = 0; t < 32; ++t) {
    const int buf = t & 1;
    const u16* pA = &lds[buf][0][wr][0];
    const u16* pB = &lds[buf][1][wc >> 1][(wc & 1) << 12];
    const int jb = 4 * t + 7;

    // ---- P1: issue b1 reads (for P2); stage; MFMA Q00 (a_lo x b0)
#pragma unroll
    for (int ni = 0; ni < 2; ++ni)
#pragma unroll
      for (int ks = 0; ks < 2; ++ks)
        b1[ni][ks] = *(const bf16x8*)(pB + ((2 + ni) << 10) + rbase + co[ks]);
    if (jb < 128) stage(jb);
    __builtin_amdgcn_s_setprio(1);
#pragma unroll
    for (int mi = 0; mi < 4; ++mi)
#pragma unroll
      for (int ni = 0; ni < 2; ++ni)
#pragma unroll
        for (int ks = 0; ks < 2; ++ks)
          acc[mi][ni] = MFMA(a[mi][ks], b0[ni][ks], acc[mi][ni], 0, 0, 0);
    __builtin_amdgcn_s_setprio(0);
    __builtin_amdgcn_s_barrier();

    // ---- P2: issue a_hi reads (for P3); stage; MFMA Q01 (a_lo x b1)
#pragma unroll
    for (int mi = 0; mi < 4; ++mi)
#pragma unroll
      for (int ks = 0; ks < 2; ++ks)
        a2[mi][ks] = *(const bf16x8*)(pA + ((4 + mi) << 10) + rbase + co[ks]);
    if (jb + 1 < 128) stage(jb + 1);
    __builtin_amdgcn_s_setprio(1);
#pragma unroll
    for (int mi = 0; mi < 4; ++mi)
#pragma unroll
      for (int ni = 0; ni < 2; ++ni)
#pragma unroll
        for (int ks = 0; ks < 2; ++ks)
          acc[mi][2 + ni] = MFMA(a[mi][ks], b1[ni][ks], acc[mi][2 + ni], 0, 0, 0);
    __builtin_amdgcn_s_setprio(0);
    __builtin_amdgcn_s_barrier();

    // ---- P3: stage; MFMA Q11 (a_hi x b1)
    if (jb + 2 < 128) stage(jb + 2);
    __builtin_amdgcn_s_setprio(1);
#pragma unroll
    for (int mi = 0; mi < 4; ++mi)
#pragma unroll
      for (int ni = 0; ni < 2; ++ni)
#pragma unroll
        for (int ks = 0; ks < 2; ++ks)
          acc[4 + mi][2 + ni] = MFMA(a2[mi][ks], b1[ni][ks], acc[4 + mi][2 + ni], 0, 0, 0);
    __builtin_amdgcn_s_setprio(0);
    __builtin_amdgcn_s_barrier();

    // ---- P4: stage; vmcnt (tile t+1 landed); barrier; issue next-tile
    // a_lo/b0 reads (buf^1 -- disjoint from in-flight stage writes to buf);
    // MFMA Q10 on held regs (a_hi x b0).
    if (jb + 3 < 128) stage(jb + 3);
    if (t < 30) asm volatile("s_waitcnt vmcnt(6)" ::: "memory");
    else        asm volatile("s_waitcnt vmcnt(0)" ::: "memory");
    __builtin_amdgcn_s_barrier();
    if (t < 31) {
      const u16* qA = &lds[buf ^ 1][0][wr][0];
      const u16* qB = &lds[buf ^ 1][1][wc >> 1][(wc & 1) << 12];
#pragma unroll
      for (int mi = 0; mi < 4; ++mi)
#pragma unroll
        for (int ks = 0; ks < 2; ++ks)
          aN[mi][ks] = *(const bf16x8*)(qA + (mi << 10) + rbase + co[ks]);
#pragma unroll
      for (int ni = 0; ni < 2; ++ni)
#pragma unroll
        for (int ks = 0; ks < 2; ++ks)
          b0N[ni][ks] = *(const bf16x8*)(qB + (ni << 10) + rbase + co[ks]);
    }
    __builtin_amdgcn_s_setprio(1);
#pragma unroll
    for (int mi = 0; mi < 4; ++mi)
#pragma unroll
      for (int ni = 0; ni < 2; ++ni)
#pragma unroll
        for (int ks = 0; ks < 2; ++ks)
          acc[4 + mi][ni] = MFMA(a2[mi][ks], b0[ni][ks], acc[4 + mi][ni], 0, 0, 0);
    __builtin_amdgcn_s_setprio(0);
    // rotate pipelined regs (renamed away by the unroll-2)
    if (t < 31) {
#pragma unroll
      for (int mi = 0; mi < 4; ++mi)
#pragma unroll
        for (int ks = 0; ks < 2; ++ks)
          a[mi][ks] = aN[mi][ks];
#pragma unroll
      for (int ni = 0; ni < 2; ++ni)
#pragma unroll
        for (int ks = 0; ks < 2; ++ks)
          b0[ni][ks] = b0N[ni][ks];
    }
  }

  // ---- Epilogue: activation + fused 16-step chunk scan + packed stores.
  // C/D frag: col16 = lane&15, row16 = (lane>>4)*4 + r  ->  t = frag-row,
  // b = row16, channel h = n>>1, z/f split by lane parity.
  const int colp = lane & 15;
  const bool isz = (colp & 1) == 0;
  const float kk = isz ? 1.702f : 1.0f;
  const int jj = colp >> 1;               // h & 7
  const int b4 = lane >> 4;               // b >> 2
  const int hbase = ((n0 + (wc << 6)) >> 1) + jj;   // + 8*ni
  const int c    = m0 >> 8;               // chunk id
  const int nfb  = (n0 >> 4) + (wc << 2); // frag-col base, + ni
  float* exA = (float*)&lds[0][0][0][0];  // 8 KB, reuse dead staging LDS
  float* exB = exA + 2048;                // 8 KB

  uint4 trj[8];                           // wr1: stash local trajectory per ni
#pragma unroll
  for (int ni = 0; ni < 4; ++ni) {
    float bias = isz ? bz[hbase + 8 * ni] : bfv[hbase + 8 * ni];
    float hh[4] = {0.f, 0.f, 0.f, 0.f}, P[4] = {1.f, 1.f, 1.f, 1.f};
#pragma unroll
    for (int mi = 0; mi < 8; ++mi) {
      unsigned tw[4];
#pragma unroll
      for (int r = 0; r < 4; ++r) {
        float v = acc[mi][ni][r] + bias;
        float s = 1.f / (1.f + __expf(-kk * v));
        float act = isz ? v * s : s;            // quick_gelu : sigmoid
        float par = __shfl_xor(act, 1, 64);     // partner value (f<->z)
        float z = isz ? act : par;
        float f = isz ? par : act;
        hh[r] += f * (z - hh[r]);
        P[r]  *= (1.f - f);
        tw[r] = (unsigned)f2bf(hh[r]) | ((unsigned)f2bf(P[r]) << 16);
      }
      if (wr == 0) {
        if (!(lane & 1)) {
          size_t fi = (size_t)((c << 4) + mi) * 128 + nfb + ni;
          uint4 o; o.x = tw[0]; o.y = tw[1]; o.z = tw[2]; o.w = tw[3];
          *reinterpret_cast<uint4*>(Cb + fi * 256 + (b4 << 6) + (jj << 3)) = o;
        }
      } else {
        uint4 o; o.x = tw[0]; o.y = tw[1]; o.z = tw[2]; o.w = tw[3];
        trj[mi] = o;
      }
    }
    // exchange slot (per ni -> distinct, no WAR across ni iterations)
    const int xi = (((((wc << 2) | b4) << 3) | jj) << 2 | ni) << 2;  // + r
    if (wr == 0 && !(lane & 1)) {
#pragma unroll
      for (int r = 0; r < 4; ++r) { exA[xi + r] = hh[r]; exB[xi + r] = P[r]; }
    }
    __syncthreads();
    if (wr == 1 && !(lane & 1)) {
      float A0[4], B0[4];
#pragma unroll
      for (int r = 0; r < 4; ++r) { A0[r] = exA[xi + r]; B0[r] = exB[xi + r]; }
#pragma unroll
      for (int mi = 0; mi < 8; ++mi) {
        uint4 o;
        unsigned* ow = &o.x;
        const unsigned* iw = &trj[mi].x;
#pragma unroll
        for (int r = 0; r < 4; ++r) {
          float hp = bf2f(iw[r] & 0xffffu);
          float pp = bf2f(iw[r] >> 16);
          float H2 = hp + pp * A0[r];           // rebase onto wr0 end state
          float P2 = pp * B0[r];
          ow[r] = (unsigned)f2bf(H2) | ((unsigned)f2bf(P2) << 16);
        }
        size_t fi = (size_t)((c << 4) + 8 + mi) * 128 + nfb + ni;
        *reinterpret_cast<uint4*>(Cb + fi * 256 + (b4 << 6) + (jj << 3)) = o;
      }
    }
  }
}

// ---------------------------------------------------------------------------
// Kernel 3: final scan pass. Per (c,b4,h): recombine chunk-end words
// (t = 16cc+15 holds the chunk's (A,B)) for cc<c -- L2/L3-hot, <=63 steps --
// then a chain-free elementwise pass: out[t] = Hp_t + Pp_t * h_start.
// ---------------------------------------------------------------------------
__global__ __launch_bounds__(256) void k_scan(const u16* __restrict__ Cb,
                                              float* __restrict__ out) {
  int i = blockIdx.x * 256 + threadIdx.x;  // 262144 = NCHUNK * 4 * 1024
  int h  = i & (C_HID - 1);
  int b4 = (i >> 10) & 3;
  int c  = i >> 12;                        // block-uniform
  const size_t lane_off = (size_t)(h >> 3) * 256 + b4 * 64 + (h & 7) * 8;
  float hh[4] = {0.f, 0.f, 0.f, 0.f};
  for (int cc = 0; cc < c; ++cc) {
    uint4 w = *reinterpret_cast<const uint4*>(
        Cb + ((size_t)cc * CLEN + CLEN - 1) * 32768 + lane_off);
    const unsigned* ww = &w.x;
#pragma unroll
    for (int r = 0; r < 4; ++r) {
      float A = bf2f(ww[r] & 0xffffu), B = bf2f(ww[r] >> 16);
      hh[r] = A + B * hh[r];
    }
  }
#pragma unroll 4
  for (int tt = 0; tt < CLEN; ++tt) {
    size_t t = (size_t)c * CLEN + tt;
    uint4 w = *reinterpret_cast<const uint4*>(Cb + t * 32768 + lane_off);
    const unsigned* ww = &w.x;
    float* op = out + t * 16384 + (size_t)b4 * 4096 + h;
#pragma unroll
    for (int r = 0; r < 4; ++r) {
      float v = bf2f(ww[r] & 0xffffu) + bf2f(ww[r] >> 16) * hh[r];
      op[r * 1024] = v;
      if (c == NCHUNK - 1 && tt == CLEN - 1)
        out[(size_t)M_ROWS * C_HID + (size_t)b4 * 4096 + h + r * 1024] = v;  // H[-1]
    }
  }
}

// ---------------------------------------------------------------------------
extern "C" void kernel_launch(void* const* d_in, const int* in_sizes, int n_in,
                              void* d_out, int out_size, void* d_ws, size_t ws_size,
                              hipStream_t stream) {
  const float* X   = (const float*)d_in[0];
  const float* Wz  = (const float*)d_in[1];
  const float* bz  = (const float*)d_in[2];
  const float* Wf  = (const float*)d_in[3];
  const float* bf_ = (const float*)d_in[4];
  float* out = (float*)d_out;

  // workspace layout (bf16 = u16):
  u16* Xp = (u16*)d_ws;                                 // (16384+16)*1024 u16
  u16* Wt = Xp + (size_t)(M_ROWS + B_SZ) * C_IN;        // 2048*2048 u16
  u16* Cb = Wt + (size_t)N_COLS * K_DIM;                // 16384*2048 u16 (blocked)

  hipLaunchKernelGGL(k_prep, dim3(16400 + 8192), dim3(256), 0, stream,
                     X, Wz, Wf, Xp, Wt);
  hipLaunchKernelGGL(k_gemm8, dim3((M_ROWS / 256) * (N_COLS / 256)), dim3(512), 0,
                     stream, Xp, Wt, bz, bf_, Cb);
  hipLaunchKernelGGL(k_scan, dim3(NCHUNK * 4096 / 256), dim3(256), 0, stream,
                     Cb, out);
}

// Round 10
// 295.994 us; speedup vs baseline: 1.3290x; 1.3290x over previous
//
#include <hip/hip_runtime.h>
#include <stdint.h>

// Problem constants
#define T_SEQ 1024
#define B_SZ  16
#define C_IN  1024
#define C_HID 1024
#define M_ROWS (T_SEQ * B_SZ)   // 16384
#define N_COLS (2 * C_HID)      // 2048  (col 2h = Z_h, col 2h+1 = F_h)
#define K_DIM  (2 * C_IN)       // 2048  (k<1024: X[t-1], k>=1024: X[t])

#define NCHUNK 64
#define CLEN   (T_SEQ / NCHUNK) // 16 = rows-per-GEMM-block / B_SZ -> 1 chunk/block
#define NBH    (B_SZ * C_HID)   // 16384 channels

typedef __attribute__((ext_vector_type(8))) short bf16x8;
typedef __attribute__((ext_vector_type(4))) float f32x4;
typedef unsigned short u16;

#define MFMA __builtin_amdgcn_mfma_f32_16x16x32_bf16

__device__ __forceinline__ u16 f2bf(float f) {
  union { float f; unsigned u; } v; v.f = f;
  unsigned r = v.u + 0x7fffu + ((v.u >> 16) & 1u);  // RNE
  return (u16)(r >> 16);
}
__device__ __forceinline__ float bf2f(unsigned s) {
  union { unsigned u; float f; } v; v.u = s << 16;
  return v.f;
}

// async global->LDS, 16B per lane. LDS dest is wave-uniform base + lane*16.
__device__ __forceinline__ void async_cp16(const u16* g, u16* l) {
  __builtin_amdgcn_global_load_lds(
      (const __attribute__((address_space(1))) unsigned*)(uintptr_t)g,
      (__attribute__((address_space(3))) unsigned*)(uintptr_t)l,
      16, 0, 0);
}

// ---------------------------------------------------------------------------
// Kernel 1 (fused prep): blocks [0,16400) convert X f32->bf16 with one
// leading zero time-step; blocks [16400,24592) repack Wz/Wf -> Wt
// (N=2048,K=2048) bf16 B^T, Z/F interleaved (row 2h = Wz[h], 2h+1 = Wf[h]).
// ---------------------------------------------------------------------------
__global__ __launch_bounds__(256) void k_prep(const float* __restrict__ X,
                                              const float* __restrict__ Wz,
                                              const float* __restrict__ Wf,
                                              u16* __restrict__ Xp,
                                              u16* __restrict__ Wt) {
  int blk = blockIdx.x;
  if (blk < 16400) {
    int i = blk * 256 + threadIdx.x;            // one thread = 4 elems
    const int total4 = (M_ROWS + B_SZ) * C_IN / 4;
    if (i >= total4) return;
    int e = i << 2;
    const int PAD = B_SZ * C_IN;  // 16384
    ushort4 o;
    if (e < PAD) {
      o.x = o.y = o.z = o.w = 0;
    } else {
      float4 v = *reinterpret_cast<const float4*>(X + (e - PAD));
      o.x = f2bf(v.x); o.y = f2bf(v.y); o.z = f2bf(v.z); o.w = f2bf(v.w);
    }
    *reinterpret_cast<ushort4*>(Xp + e) = o;
  } else {
    int i = (blk - 16400) * 256 + threadIdx.x;  // one thread = one (g,h,c)
    if (i >= 2 * 1024 * 1024) return;
    int g  = i >> 20;
    int hc = i & ((1 << 20) - 1);
    int h  = hc >> 10;
    int c  = hc & 1023;
    const float* W = g ? Wf : Wz;
    float2 w = *reinterpret_cast<const float2*>(W + ((size_t)(h << 10) + c) * 2);
    size_t n = ((size_t)h << 1) | (size_t)g;   // interleave Z/F
    Wt[n * K_DIM + c]        = f2bf(w.x);      // k = 0 tap
    Wt[n * K_DIM + 1024 + c] = f2bf(w.y);      // k = 1 tap
  }
}

// ---------------------------------------------------------------------------
// Kernel 2: 256x256-tile bf16 GEMM. Round-8 register footprint (116 arch +
// 128 acc = 244/256 -- the r9 post-mortem constraint: no pipeline buffers fit).
// Round-10 K-loop changes (zero extra registers):
//  * NO explicit lgkmcnt(0) drains -- compiler emits COUNTED lgkm waits per
//    MFMA operand, so later ds_reads are serviced during the MFMA cluster.
//  * ONE barrier per phase (4/tile, was 8). WAR audit (region: last reader /
//    overwriting stage): t+1.A1 read@t-1.P3, staged@t.P1; t+2.B0 read@t.P1,
//    staged@t.P2; t+2.B1 read@t.P2, staged@t.P3; t+2.A0 read@t.P3(a_hi),
//    staged@t.P4. Counted waits drain each phase's reads before its MFMA
//    cluster ends; the phase-end barrier precedes each overwrite. vmcnt(6)@P4
//    still proves tile t+1 landed (its last part staged at P1 => the 6
//    allowed-outstanding ops are P2/P3/P4's stages, all tile t+2).
//  * P4 runs MFMA Q10 (register-only) BEFORE the vmcnt stall.
// Epilogue (round-8 verified): activation + in-register 16-step chunk scan;
// Cb word = bf16(Hpart) | bf16(Ppre)<<16,  h_t(h0) = Hpart + Ppre*h0.
// ---------------------------------------------------------------------------
__global__ __launch_bounds__(512, 2) void k_gemm8(const u16* __restrict__ Xp,
                                                  const u16* __restrict__ Wt,
                                                  const float* __restrict__ bz,
                                                  const float* __restrict__ bfv,
                                                  u16* __restrict__ Cb) {
  __shared__ u16 lds[2][2][2][8192];  // [buf][A=0/B=1][half][128*64] = 128 KiB
  const int tid  = threadIdx.x;
  const int lane = tid & 63;
  const int wid  = tid >> 6;
  const int wr = wid >> 2;        // m-half of this wave
  const int wc = wid & 3;         // n-quarter
  const int lr = lane & 15;

  // T1: XCD-bijective swizzle (512 blocks, 512%8==0), n-fastest within XCD
  int wg = (blockIdx.x & 7) * 64 + (blockIdx.x >> 3);
  const int m0 = (wg >> 3) << 8;
  const int n0 = (wg & 7) << 8;

  // staging per-thread coords: linear LDS byte p -> logical source byte q
  const int p    = tid << 4;
  const int q    = p ^ (((p >> 7) & 7) << 4);   // involution (bits 4-6 vs 7-9)
  const int grow = q >> 7;                      // logical row 0..63 (issue 0)
  const int gcol = (q & 127) >> 1;              // logical col element
  const int ldsw = (tid >> 6) << 9;             // u16 wave base (wid*1KB)

  // ds_read per-thread coords (u16 units), swizzled column offset
  const int rbase = lr << 6;
  int co[2];
#pragma unroll
  for (int ks = 0; ks < 2; ++ks)
    co[ks] = ((((ks << 6) | ((lane >> 4) << 4)) ^ ((lr & 7) << 4)) >> 1);

  auto stage = [&](int j) {   // j = 4*kt + {0:B0,1:B1,2:A0,3:A1}
    int kt = j >> 2, part = j & 3, buf = kt & 1;
    if (part >= 2) {
      int h = part - 2;
      const u16* g = Xp + (size_t)(m0 + (h << 7) + grow + ((kt >= 16) ? B_SZ : 0)) * C_IN
                        + ((kt & 15) << 6) + gcol;
      u16* l = &lds[buf][0][h][ldsw];
      async_cp16(g, l);
      async_cp16(g + (size_t)64 * C_IN, l + 4096);
    } else {
      const u16* g = Wt + (size_t)(n0 + (part << 7) + grow) * K_DIM + (kt << 6) + gcol;
      u16* l = &lds[buf][1][part][ldsw];
      async_cp16(g, l);
      async_cp16(g + (size_t)64 * K_DIM, l + 4096);
    }
  };

  f32x4 acc[8][4] = {};
  bf16x8 a[4][2], b0[2][2], b1[2][2];

  // prologue: stage tile0 + tile1 B0,B1,A0 (j0..6); tile0 landed at vmcnt(6)
  for (int j = 0; j < 7; ++j) stage(j);
  asm volatile("s_waitcnt vmcnt(6)" ::: "memory");
  __builtin_amdgcn_s_barrier();

#pragma unroll 2
  for (int t = 0; t < 32; ++t) {
    const int buf = t & 1;
    const u16* pA = &lds[buf][0][wr][0];
    const u16* pB = &lds[buf][1][wc >> 1][(wc & 1) << 12];
    const int jb = 4 * t + 7;

    // ---- P1: read a_lo + b0; stage; MFMA Q00 (counted lgkm waits)
#pragma unroll
    for (int mi = 0; mi < 4; ++mi)
#pragma unroll
      for (int ks = 0; ks < 2; ++ks)
        a[mi][ks] = *(const bf16x8*)(pA + (mi << 10) + rbase + co[ks]);
#pragma unroll
    for (int ni = 0; ni < 2; ++ni)
#pragma unroll
      for (int ks = 0; ks < 2; ++ks)
        b0[ni][ks] = *(const bf16x8*)(pB + (ni << 10) + rbase + co[ks]);
    if (jb < 128) stage(jb);
    __builtin_amdgcn_s_setprio(1);
#pragma unroll
    for (int mi = 0; mi < 4; ++mi)
#pragma unroll
      for (int ni = 0; ni < 2; ++ni)
#pragma unroll
        for (int ks = 0; ks < 2; ++ks)
          acc[mi][ni] = MFMA(a[mi][ks], b0[ni][ks], acc[mi][ni], 0, 0, 0);
    __builtin_amdgcn_s_setprio(0);
    __builtin_amdgcn_s_barrier();

    // ---- P2: read b1; stage; MFMA Q01
#pragma unroll
    for (int ni = 0; ni < 2; ++ni)
#pragma unroll
      for (int ks = 0; ks < 2; ++ks)
        b1[ni][ks] = *(const bf16x8*)(pB + ((2 + ni) << 10) + rbase + co[ks]);
    if (jb + 1 < 128) stage(jb + 1);
    __builtin_amdgcn_s_setprio(1);
#pragma unroll
    for (int mi = 0; mi < 4; ++mi)
#pragma unroll
      for (int ni = 0; ni < 2; ++ni)
#pragma unroll
        for (int ks = 0; ks < 2; ++ks)
          acc[mi][2 + ni] = MFMA(a[mi][ks], b1[ni][ks], acc[mi][2 + ni], 0, 0, 0);
    __builtin_amdgcn_s_setprio(0);
    __builtin_amdgcn_s_barrier();

    // ---- P3: read a_hi (reuse a[]); stage; MFMA Q11
#pragma unroll
    for (int mi = 0; mi < 4; ++mi)
#pragma unroll
      for (int ks = 0; ks < 2; ++ks)
        a[mi][ks] = *(const bf16x8*)(pA + ((4 + mi) << 10) + rbase + co[ks]);
    if (jb + 2 < 128) stage(jb + 2);
    __builtin_amdgcn_s_setprio(1);
#pragma unroll
    for (int mi = 0; mi < 4; ++mi)
#pragma unroll
      for (int ni = 0; ni < 2; ++ni)
#pragma unroll
        for (int ks = 0; ks < 2; ++ks)
          acc[4 + mi][2 + ni] = MFMA(a[mi][ks], b1[ni][ks], acc[4 + mi][2 + ni], 0, 0, 0);
    __builtin_amdgcn_s_setprio(0);
    __builtin_amdgcn_s_barrier();

    // ---- P4: stage; MFMA Q10 on held regs (before the vmcnt stall); then
    // vmcnt proves tile t+1 landed; single barrier closes the tile.
    if (jb + 3 < 128) stage(jb + 3);
    __builtin_amdgcn_s_setprio(1);
#pragma unroll
    for (int mi = 0; mi < 4; ++mi)
#pragma unroll
      for (int ni = 0; ni < 2; ++ni)
#pragma unroll
        for (int ks = 0; ks < 2; ++ks)
          acc[4 + mi][ni] = MFMA(a[mi][ks], b0[ni][ks], acc[4 + mi][ni], 0, 0, 0);
    __builtin_amdgcn_s_setprio(0);
    if (t < 30) asm volatile("s_waitcnt vmcnt(6)" ::: "memory");
    else        asm volatile("s_waitcnt vmcnt(0)" ::: "memory");
    __builtin_amdgcn_s_barrier();
  }

  // ---- Epilogue: activation + fused 16-step chunk scan + packed stores.
  // C/D frag: col16 = lane&15, row16 = (lane>>4)*4 + r  ->  t = frag-row,
  // b = row16, channel h = n>>1, z/f split by lane parity.
  const int colp = lane & 15;
  const bool isz = (colp & 1) == 0;
  const float kk = isz ? 1.702f : 1.0f;
  const int jj = colp >> 1;               // h & 7
  const int b4 = lane >> 4;               // b >> 2
  const int hbase = ((n0 + (wc << 6)) >> 1) + jj;   // + 8*ni
  const int c    = m0 >> 8;               // chunk id
  const int nfb  = (n0 >> 4) + (wc << 2); // frag-col base, + ni
  float* exA = (float*)&lds[0][0][0][0];  // 8 KB, reuse dead staging LDS
  float* exB = exA + 2048;                // 8 KB

  uint4 trj[8];                           // wr1: stash local trajectory per ni
#pragma unroll
  for (int ni = 0; ni < 4; ++ni) {
    float bias = isz ? bz[hbase + 8 * ni] : bfv[hbase + 8 * ni];
    float hh[4] = {0.f, 0.f, 0.f, 0.f}, P[4] = {1.f, 1.f, 1.f, 1.f};
#pragma unroll
    for (int mi = 0; mi < 8; ++mi) {
      unsigned tw[4];
#pragma unroll
      for (int r = 0; r < 4; ++r) {
        float v = acc[mi][ni][r] + bias;
        float s = 1.f / (1.f + __expf(-kk * v));
        float act = isz ? v * s : s;            // quick_gelu : sigmoid
        float par = __shfl_xor(act, 1, 64);     // partner value (f<->z)
        float z = isz ? act : par;
        float f = isz ? par : act;
        hh[r] += f * (z - hh[r]);
        P[r]  *= (1.f - f);
        tw[r] = (unsigned)f2bf(hh[r]) | ((unsigned)f2bf(P[r]) << 16);
      }
      if (wr == 0) {
        if (!(lane & 1)) {
          size_t fi = (size_t)((c << 4) + mi) * 128 + nfb + ni;
          uint4 o; o.x = tw[0]; o.y = tw[1]; o.z = tw[2]; o.w = tw[3];
          *reinterpret_cast<uint4*>(Cb + fi * 256 + (b4 << 6) + (jj << 3)) = o;
        }
      } else {
        uint4 o; o.x = tw[0]; o.y = tw[1]; o.z = tw[2]; o.w = tw[3];
        trj[mi] = o;
      }
    }
    // exchange slot (per ni -> distinct, no WAR across ni iterations)
    const int xi = (((((wc << 2) | b4) << 3) | jj) << 2 | ni) << 2;  // + r
    if (wr == 0 && !(lane & 1)) {
#pragma unroll
      for (int r = 0; r < 4; ++r) { exA[xi + r] = hh[r]; exB[xi + r] = P[r]; }
    }
    __syncthreads();
    if (wr == 1 && !(lane & 1)) {
      float A0[4], B0[4];
#pragma unroll
      for (int r = 0; r < 4; ++r) { A0[r] = exA[xi + r]; B0[r] = exB[xi + r]; }
#pragma unroll
      for (int mi = 0; mi < 8; ++mi) {
        uint4 o;
        unsigned* ow = &o.x;
        const unsigned* iw = &trj[mi].x;
#pragma unroll
        for (int r = 0; r < 4; ++r) {
          float hp = bf2f(iw[r] & 0xffffu);
          float pp = bf2f(iw[r] >> 16);
          float H2 = hp + pp * A0[r];           // rebase onto wr0 end state
          float P2 = pp * B0[r];
          ow[r] = (unsigned)f2bf(H2) | ((unsigned)f2bf(P2) << 16);
        }
        size_t fi = (size_t)((c << 4) + 8 + mi) * 128 + nfb + ni;
        *reinterpret_cast<uint4*>(Cb + fi * 256 + (b4 << 6) + (jj << 3)) = o;
      }
    }
  }
}

// ---------------------------------------------------------------------------
// Kernel 3: final scan pass. Per (c,b4,h): recombine chunk-end words
// (t = 16cc+15 holds the chunk's (A,B)) for cc<c -- L2/L3-hot, <=63 steps --
// then a chain-free elementwise pass: out[t] = Hp_t + Pp_t * h_start.
// ---------------------------------------------------------------------------
__global__ __launch_bounds__(256) void k_scan(const u16* __restrict__ Cb,
                                              float* __restrict__ out) {
  int i = blockIdx.x * 256 + threadIdx.x;  // 262144 = NCHUNK * 4 * 1024
  int h  = i & (C_HID - 1);
  int b4 = (i >> 10) & 3;
  int c  = i >> 12;                        // block-uniform
  const size_t lane_off = (size_t)(h >> 3) * 256 + b4 * 64 + (h & 7) * 8;
  float hh[4] = {0.f, 0.f, 0.f, 0.f};
  for (int cc = 0; cc < c; ++cc) {
    uint4 w = *reinterpret_cast<const uint4*>(
        Cb + ((size_t)cc * CLEN + CLEN - 1) * 32768 + lane_off);
    const unsigned* ww = &w.x;
#pragma unroll
    for (int r = 0; r < 4; ++r) {
      float A = bf2f(ww[r] & 0xffffu), B = bf2f(ww[r] >> 16);
      hh[r] = A + B * hh[r];
    }
  }
#pragma unroll 4
  for (int tt = 0; tt < CLEN; ++tt) {
    size_t t = (size_t)c * CLEN + tt;
    uint4 w = *reinterpret_cast<const uint4*>(Cb + t * 32768 + lane_off);
    const unsigned* ww = &w.x;
    float* op = out + t * 16384 + (size_t)b4 * 4096 + h;
#pragma unroll
    for (int r = 0; r < 4; ++r) {
      float v = bf2f(ww[r] & 0xffffu) + bf2f(ww[r] >> 16) * hh[r];
      op[r * 1024] = v;
      if (c == NCHUNK - 1 && tt == CLEN - 1)
        out[(size_t)M_ROWS * C_HID + (size_t)b4 * 4096 + h + r * 1024] = v;  // H[-1]
    }
  }
}

// ---------------------------------------------------------------------------
extern "C" void kernel_launch(void* const* d_in, const int* in_sizes, int n_in,
                              void* d_out, int out_size, void* d_ws, size_t ws_size,
                              hipStream_t stream) {
  const float* X   = (const float*)d_in[0];
  const float* Wz  = (const float*)d_in[1];
  const float* bz  = (const float*)d_in[2];
  const float* Wf  = (const float*)d_in[3];
  const float* bf_ = (const float*)d_in[4];
  float* out = (float*)d_out;

  // workspace layout (bf16 = u16):
  u16* Xp = (u16*)d_ws;                                 // (16384+16)*1024 u16
  u16* Wt = Xp + (size_t)(M_ROWS + B_SZ) * C_IN;        // 2048*2048 u16
  u16* Cb = Wt + (size_t)N_COLS * K_DIM;                // 16384*2048 u16 (blocked)

  hipLaunchKernelGGL(k_prep, dim3(16400 + 8192), dim3(256), 0, stream,
                     X, Wz, Wf, Xp, Wt);
  hipLaunchKernelGGL(k_gemm8, dim3((M_ROWS / 256) * (N_COLS / 256)), dim3(512), 0,
                     stream, Xp, Wt, bz, bf_, Cb);
  hipLaunchKernelGGL(k_scan, dim3(NCHUNK * 4096 / 256), dim3(256), 0, stream,
                     Cb, out);
}